// Round 4
// baseline (196.200 us; speedup 1.0000x reference)
//
#include <hip/hip_runtime.h>

#define NPTS 65536
#define NB 32
#define H 256
#define K2E 2.8853900817779268f   // 2*log2(e): tanh(z)=1-2/(exp2(K2E*z)+1)

typedef __attribute__((ext_vector_type(8))) short bhalf8;   // 8 bf16 = 4 VGPRs
typedef __attribute__((ext_vector_type(4))) float f32x4;

union BHU { bhalf8 h; uint u[4]; };

__device__ __forceinline__ float bf2f(ushort u) {
  union { uint x; float f; } c; c.x = ((uint)u) << 16; return c.f;
}
__device__ __forceinline__ ushort f2bf(float f) {            // RNE (final outputs only)
  uint x = __float_as_uint(f);
  uint r = x + 0x7FFFu + ((x >> 16) & 1u);
  return (ushort)(r >> 16);
}
__device__ __forceinline__ uint packrne(float a, float b) {
  return (uint)f2bf(a) | ((uint)f2bf(b) << 16);
}
// truncating bf16 — MFMA inputs / LDS intermediates only
__device__ __forceinline__ ushort trunc1(float f) {
  return (ushort)(__float_as_uint(f) >> 16);
}
__device__ __forceinline__ uint packtr(float a, float b) {
  return (__float_as_uint(a) >> 16) | (__float_as_uint(b) & 0xFFFF0000u);
}
// tanh with pre-folded 2*log2e arg: v_exp + v_add + v_rcp + v_fma (no div sequence!)
__device__ __forceinline__ float tanh_pf(float z2e) {
  float e = exp2f(z2e);
  float r = __builtin_amdgcn_rcpf(e + 1.0f);
  return fmaf(-2.0f, r, 1.0f);
}

// dtype detect from W1 bit pattern (wave-uniform)
__device__ __forceinline__ bool detect_bf16(const void* W1) {
  const uint4* p = (const uint4*)W1;
  int cnt = 0;
#pragma unroll
  for (int i = 0; i < 8; i++) {
    uint4 v = p[i];
    uint d[4] = {v.x, v.y, v.z, v.w};
#pragma unroll
    for (int k = 0; k < 4; k++) {
      int e = (d[k] >> 7) & 0xFF;                 // exponent of low halfword
      cnt += (e >= 0x70 && e <= 0x7E) ? 1 : 0;
    }
  }
  return cnt >= 16;
}

template<bool B16> __device__ __forceinline__ float LD(const void* p, int i) {
  if constexpr (B16) return bf2f(((const ushort*)p)[i]);
  else               return ((const float*)p)[i];
}
template<bool B16> __device__ __forceinline__ void ST(void* p, int i, float v) {
  if constexpr (B16) ((ushort*)p)[i] = f2bf(v);
  else               ((float*)p)[i] = v;
}

// Pre-swizzle W1 [256][256], W2 [256][32] into MFMA B-frag order (bf16):
// frag(ct,kk): lane l=q*16+r holds B[kk*32+q*8+j][ct*16+r], j=0..7.
__global__ void swz_kernel(const void* W1, const void* W2,
                           ushort* __restrict__ W1s, ushort* __restrict__ W2s) {
  int gid = blockIdx.x * 256 + threadIdx.x;
  bool b16 = detect_bf16(W1);
  if (gid < 65536) {
    int r = gid & 15, q = (gid >> 4) & 3, j = (gid >> 6) & 7;
    int kk = (gid >> 9) & 7, ct = gid >> 12;
    int src = (kk * 32 + q * 8 + j) * H + ct * 16 + r;
    int dst = ((ct * 8 + kk) * 64 + q * 16 + r) * 8 + j;
    float v = b16 ? bf2f(((const ushort*)W1)[src]) : ((const float*)W1)[src];
    W1s[dst] = f2bf(v);
  } else {
    int g2 = gid - 65536;
    int r = g2 & 15, q = (g2 >> 4) & 3, j = (g2 >> 6) & 7;
    int kk = (g2 >> 9) & 7, ct = (g2 >> 12) & 1;
    int src = (kk * 32 + q * 8 + j) * NB + ct * 16 + r;
    int dst = ((ct * 8 + kk) * 64 + q * 16 + r) * 8 + j;
    float v = b16 ? bf2f(((const ushort*)W2)[src]) : ((const float*)W2)[src];
    W2s[dst] = f2bf(v);
  }
}

#define PPITCH 40    // bf16 cols: 80B rows, b128-aligned

// LDS layout (38272 B <= 40KB -> 4 blocks/CU LDS-wise; grid=1024 -> ALL resident):
//   pairw: wave-private h1 chunk (rows 0..31 reused for sin/cos in epilogue)
//   w1st : 2-buffer ring of one-ct W1 B-frag chunks (8KB each), block-shared,
//          filled by global_load_lds; depth-1 prefetch makes vmcnt(0) exact
struct Smem {
  alignas(16) ushort pairw[4][48 * PPITCH];  // 15360 B
  alignas(16) ushort w1st[2][4096];          // 16384 B
  alignas(16) ushort lamTf[2 * 64 * 8];      //  2048 B lambda^T B-frags
  alignas(16) float  w0d[H], w0e[H], b0e[H], b1e[H]; // 4096 B (w0d = 0.1*w0 pre-folded)
  alignas(16) float  b2c[NB], lamMc[NB], lamDc[NB]; // 384 B
};                                           // 38272 B

// Stage one ct's 8KB W1-frag chunk into an LDS ring buffer.
// Dest is wave-uniform base (HW adds lane*16B); src is per-lane. 2 issues/wave.
__device__ __forceinline__ void stage_ct(const ushort* __restrict__ W1s,
                                         ushort* buf, int ct, int wave, int lane) {
#pragma unroll
  for (int c = 0; c < 2; c++) {
    const ushort* src = W1s + ct * 4096 + (wave * 2 + c) * 512 + lane * 8;
    ushort* dst = buf + (wave * 2 + c) * 512;   // wave-uniform
    __builtin_amdgcn_global_load_lds(
        (const __attribute__((address_space(1))) unsigned int*)src,
        (__attribute__((address_space(3))) unsigned int*)dst, 16, 0, 0);
  }
}

// GEMM1 for one ct. B-frags 2-deep streamed (bx/by, 8 regs) — register diet:
// target total alloc (arch+AGPR) <= 128 so HW grants the 4-waves/SIMD band
// (occupancy bands are {<=64:8, <=128:4, <=256:2} waves/SIMD — m68/m69).
__device__ __forceinline__ void gemm1(const ushort* __restrict__ buf, int lane,
                                      const bhalf8* a0f, const bhalf8* a1f,
                                      const bhalf8* a2f,
                                      f32x4& c0, f32x4& c1, f32x4& c2) {
  f32x4 z = {0.f, 0.f, 0.f, 0.f};
  c0 = z; c1 = z; c2 = z;
  const bhalf8* bp = (const bhalf8*)buf + lane;
  bhalf8 bx = bp[0 * 64];
  bhalf8 by = bp[1 * 64];
#pragma unroll
  for (int kk = 0; kk < 8; kk += 2) {
    __builtin_amdgcn_s_setprio(1);
    c0 = __builtin_amdgcn_mfma_f32_16x16x32_bf16(a0f[kk], bx, c0, 0, 0, 0);
    c1 = __builtin_amdgcn_mfma_f32_16x16x32_bf16(a1f[kk], bx, c1, 0, 0, 0);
    c2 = __builtin_amdgcn_mfma_f32_16x16x32_bf16(a2f[kk], bx, c2, 0, 0, 0);
    __builtin_amdgcn_s_setprio(0);
    if (kk < 6) bx = bp[(kk + 2) * 64];
    __builtin_amdgcn_s_setprio(1);
    c0 = __builtin_amdgcn_mfma_f32_16x16x32_bf16(a0f[kk + 1], by, c0, 0, 0, 0);
    c1 = __builtin_amdgcn_mfma_f32_16x16x32_bf16(a1f[kk + 1], by, c1, 0, 0, 0);
    c2 = __builtin_amdgcn_mfma_f32_16x16x32_bf16(a2f[kk + 1], by, c2, 0, 0, 0);
    __builtin_amdgcn_s_setprio(0);
    if (kk < 6) by = bp[(kk + 3) * 64];
  }
}

// tanh chain for one ct -> pw column lc
__device__ __forceinline__ void chain(ushort* pw, float b1v, int q, int lc,
                                      const f32x4& c0, const f32x4& c1,
                                      const f32x4& c2) {
#pragma unroll
  for (int i = 0; i < 4; i++) {
    float hv  = tanh_pf(fmaf(c0[i], K2E, b1v));
    float s2  = 1.0f - hv * hv;
    float hd  = s2 * c1[i];
    float hdd = s2 * c2[i] - 2.0f * hv * hd * c1[i];
    int row = q * 4 + i;
    pw[row * PPITCH + lc]        = trunc1(hv);
    pw[(16 + row) * PPITCH + lc] = trunc1(hd);
    pw[(32 + row) * PPITCH + lc] = trunc1(hdd);
  }
}

template<bool B16>
__device__ void pinn_body(Smem& sm,
                          const void* timeP, const void* powerP,
                          const void* W0, const void* b0,
                          const void* b1, const void* b2,
                          const void* lam_m, const void* lam_d,
                          const void* lam_b, const void* bwi,
                          const ushort* __restrict__ W1s, void* outP) {
  const int tid = threadIdx.x;
  const int wave = tid >> 6, lane = tid & 63;
  const int q = lane >> 4, r = lane & 15;
  const ushort* W2s = W1s + H * H;

  // prologue stage: ct=0 into buf0 — latency hides under the whole preamble
  stage_ct(W1s, &sm.w1st[0][0], 0, wave, lane);

  // ================= preamble (one barrier) =================
  if (tid < 128) {   // lambda^T B-frags: lane holds lam_b[ct*16+r][q*8+j]
    int ct = tid >> 6, l2 = tid & 63, qq = l2 >> 4, rr = l2 & 15;
    BHU t;
#pragma unroll
    for (int j = 0; j < 8; j += 2)
      t.u[j >> 1] = packrne(LD<B16>(lam_b, (ct * 16 + rr) * NB + qq * 8 + j),
                            LD<B16>(lam_b, (ct * 16 + rr) * NB + qq * 8 + j + 1));
    *(bhalf8*)(sm.lamTf + tid * 8) = t.h;
  }
  if (tid < H) {
    float w0v = LD<B16>(W0, tid);
    sm.w0d[tid] = 0.1f * w0v;          // pre-fold the 2/TMAX chain-rule factor
    sm.w0e[tid] = K2E * w0v;
    sm.b0e[tid] = K2E * LD<B16>(b0, tid);
    sm.b1e[tid] = K2E * LD<B16>(b1, tid);
  }
  if (tid < NB) {
    sm.b2c[tid]   = LD<B16>(b2, tid);
    sm.lamMc[tid] = LD<B16>(lam_m, tid) * LD<B16>(bwi, tid);
    sm.lamDc[tid] = LD<B16>(lam_d, tid);
  }
  __syncthreads();   // full drain once — prologue stage completes here too

  // ================= per-wave sample tile =================
  const int s0 = (blockIdx.x * 4 + wave) * 16;
  ushort* pw = &sm.pairw[wave][0];

  float t = LD<B16>(timeP, s0 + r);
  float x = t * 0.1f - 1.0f;               // 2t/TMAX - 1, TMAX = 20

  // ---- A-frags in registers: lane holds Ach[r][kk*32+q*8+j] ----
  // built in 4-wide chunks to halve the transient register peak
  bhalf8 a0f[8], a1f[8], a2f[8];
#pragma unroll
  for (int kk = 0; kk < 8; kk++) {
    BHU t0, t1, t2;
#pragma unroll
    for (int h = 0; h < 2; h++) {
      int k0 = kk * 32 + q * 8 + h * 4;
      float4 wv4 = *(const float4*)&sm.w0d[k0];
      float4 ev4 = *(const float4*)&sm.w0e[k0];
      float4 bv4 = *(const float4*)&sm.b0e[k0];
      float wv[4] = {wv4.x, wv4.y, wv4.z, wv4.w};
      float ev[4] = {ev4.x, ev4.y, ev4.z, ev4.w};
      float bv[4] = {bv4.x, bv4.y, bv4.z, bv4.w};
      float vv[4], d1v[4], d2v[4];
#pragma unroll
      for (int j = 0; j < 4; j++) {
        float v = tanh_pf(fmaf(x, ev[j], bv[j]));
        float s2 = 1.0f - v * v;
        vv[j] = v; d1v[j] = s2 * wv[j]; d2v[j] = -2.0f * v * d1v[j] * wv[j];
      }
      t0.u[h * 2 + 0] = packtr(vv[0], vv[1]); t0.u[h * 2 + 1] = packtr(vv[2], vv[3]);
      t1.u[h * 2 + 0] = packtr(d1v[0], d1v[1]); t1.u[h * 2 + 1] = packtr(d1v[2], d1v[3]);
      t2.u[h * 2 + 0] = packtr(d2v[0], d2v[1]); t2.u[h * 2 + 1] = packtr(d2v[2], d2v[3]);
    }
    a0f[kk] = t0.h; a1f[kk] = t1.h; a2f[kk] = t2.h;
  }

  // ---- fused GEMM1 -> tanh chain -> GEMM2 over LDS W1 2-buffer ring ----
  // Depth-1 prefetch: exactly one stage (2 loads) in flight across each
  // barrier, so vmcnt(0) waits only for it (no over-drain, no count fragility).
  f32x4 acc2[3][2];
#pragma unroll
  for (int ch = 0; ch < 3; ch++)
#pragma unroll
    for (int c2 = 0; c2 < 2; c2++) { f32x4 z = {0.f,0.f,0.f,0.f}; acc2[ch][c2] = z; }

  bhalf8 w2f0 = {}, w2f1 = {};   // single-buffered: loaded odd ct, used next even ct

#pragma unroll 1
  for (int ct = 0; ct < 16; ++ct) {
    asm volatile("s_waitcnt vmcnt(0)\n\ts_barrier" ::: "memory");

    if (ct < 15) stage_ct(W1s, &sm.w1st[(ct + 1) & 1][0], ct + 1, wave, lane);

    f32x4 c0, c1, c2;
    gemm1(&sm.w1st[ct & 1][0], lane, a0f, a1f, a2f, c0, c1, c2);

    if (ct & 1) {
      // issue W2 B-frags for pair pp — consumed at ct+1's GEMM2 (full-iter gap)
      int pp = ct >> 1;
      w2f0 = *(const bhalf8*)(W2s + ((0 * 8 + pp) * 64 + lane) * 8);
      w2f1 = *(const bhalf8*)(W2s + ((1 * 8 + pp) * 64 + lane) * 8);
    } else if (ct >= 2) {
      // GEMM2 for pair ct/2-1 — reads pw BEFORE chain overwrites cols 0..15;
      // hf streamed one chain at a time (register diet)
      bhalf8 hf = *(const bhalf8*)(pw + (0 * 16 + r) * PPITCH + q * 8);
      acc2[0][0] = __builtin_amdgcn_mfma_f32_16x16x32_bf16(hf, w2f0, acc2[0][0], 0, 0, 0);
      acc2[0][1] = __builtin_amdgcn_mfma_f32_16x16x32_bf16(hf, w2f1, acc2[0][1], 0, 0, 0);
      hf = *(const bhalf8*)(pw + (1 * 16 + r) * PPITCH + q * 8);
      acc2[1][0] = __builtin_amdgcn_mfma_f32_16x16x32_bf16(hf, w2f0, acc2[1][0], 0, 0, 0);
      acc2[1][1] = __builtin_amdgcn_mfma_f32_16x16x32_bf16(hf, w2f1, acc2[1][1], 0, 0, 0);
      hf = *(const bhalf8*)(pw + (2 * 16 + r) * PPITCH + q * 8);
      acc2[2][0] = __builtin_amdgcn_mfma_f32_16x16x32_bf16(hf, w2f0, acc2[2][0], 0, 0, 0);
      acc2[2][1] = __builtin_amdgcn_mfma_f32_16x16x32_bf16(hf, w2f1, acc2[2][1], 0, 0, 0);
    }

    chain(pw, sm.b1e[ct * 16 + r], q, ((ct & 1) << 4) + r, c0, c1, c2);
  }
  // final GEMM2 (pair 7) — w2f loaded at ct=15
  {
    bhalf8 hf = *(const bhalf8*)(pw + (0 * 16 + r) * PPITCH + q * 8);
    acc2[0][0] = __builtin_amdgcn_mfma_f32_16x16x32_bf16(hf, w2f0, acc2[0][0], 0, 0, 0);
    acc2[0][1] = __builtin_amdgcn_mfma_f32_16x16x32_bf16(hf, w2f1, acc2[0][1], 0, 0, 0);
    hf = *(const bhalf8*)(pw + (1 * 16 + r) * PPITCH + q * 8);
    acc2[1][0] = __builtin_amdgcn_mfma_f32_16x16x32_bf16(hf, w2f0, acc2[1][0], 0, 0, 0);
    acc2[1][1] = __builtin_amdgcn_mfma_f32_16x16x32_bf16(hf, w2f1, acc2[1][1], 0, 0, 0);
    hf = *(const bhalf8*)(pw + (2 * 16 + r) * PPITCH + q * 8);
    acc2[2][0] = __builtin_amdgcn_mfma_f32_16x16x32_bf16(hf, w2f0, acc2[2][0], 0, 0, 0);
    acc2[2][1] = __builtin_amdgcn_mfma_f32_16x16x32_bf16(hf, w2f1, acc2[2][1], 0, 0, 0);
  }

  // ---- epilogue: angles, sin/cos, coupling via MFMA, physics ----
  float dv[2][4], dt[2][4], dtt[2][4], sn[2][4], cs[2][4], Pv[2][4];
#pragma unroll
  for (int c2 = 0; c2 < 2; c2++) {
    int b = c2 * 16 + r;
    float b2v = sm.b2c[b];
#pragma unroll
    for (int i = 0; i < 4; i++) {
      int n = s0 + q * 4 + i;
      Pv[c2][i] = LD<B16>(powerP, n * NB + b);
      dv[c2][i]  = acc2[0][c2][i] + b2v;
      dt[c2][i]  = acc2[1][c2][i];
      dtt[c2][i] = acc2[2][c2][i];
      __sincosf(dv[c2][i], &sn[c2][i], &cs[c2][i]);
      // reuse pair rows: sin -> rows 0..15, cos -> rows 16..31 (after last pair read)
      pw[(q * 4 + i) * PPITCH + b]        = trunc1(sn[c2][i]);
      pw[(16 + q * 4 + i) * PPITCH + b]   = trunc1(cs[c2][i]);
      ST<B16>(outP, n * NB + b, dv[c2][i]);
      ST<B16>(outP, NPTS * NB + n * NB + b, dt[c2][i]);
    }
  }
  // coupling: C = cos @ lam^T, S = sin @ lam^T  (16x32 @ 32x32 via 16x16x32 MFMA)
  bhalf8 snA = *(const bhalf8*)(pw + r * PPITCH + q * 8);
  bhalf8 csA = *(const bhalf8*)(pw + (16 + r) * PPITCH + q * 8);
  f32x4 accC[2], accS[2];
#pragma unroll
  for (int c2 = 0; c2 < 2; c2++) {
    bhalf8 lt = *(const bhalf8*)(sm.lamTf + (c2 * 64 + lane) * 8);
    f32x4 z = {0.f,0.f,0.f,0.f};
    accC[c2] = __builtin_amdgcn_mfma_f32_16x16x32_bf16(csA, lt, z, 0, 0, 0);
    accS[c2] = __builtin_amdgcn_mfma_f32_16x16x32_bf16(snA, lt, z, 0, 0, 0);
  }
#pragma unroll
  for (int c2 = 0; c2 < 2; c2++) {
    int b = c2 * 16 + r;
    float lm = sm.lamMc[b], ld = sm.lamDc[b];
#pragma unroll
    for (int i = 0; i < 4; i++) {
      float conn = sn[c2][i] * accC[c2][i] - cs[c2][i] * accS[c2][i];
      float phys = lm * dtt[c2][i] + ld * dt[c2][i] + conn - Pv[c2][i];
      int n = s0 + q * 4 + i;
      ST<B16>(outP, 2 * NPTS * NB + n * NB + b, phys);
    }
  }
}

// (256,4): cap total alloc at 128 -> 4 waves/SIMD band. Round-2 calibration:
// AGPR ~40 hidden behind reported arch count; round-3 = 100+40 = 140 total.
// Trims here (-w2 dbuf, -bf[4]->2, -hf stream, -build temps) target ~115-125.
// Go/no-go in counters: WRITE_SIZE must stay ~24.5MB (spill tell-tale).
__global__ __launch_bounds__(256, 4)
void pinn_kernel(const void* timeP, const void* powerP,
                 const void* W0, const void* b0,
                 const void* b1, const void* b2,
                 const void* lam_m, const void* lam_d,
                 const void* lam_b, const void* bwi,
                 const void* W1_for_detect,
                 const ushort* __restrict__ W1s, void* outP) {
  __shared__ Smem sm;
  if (detect_bf16(W1_for_detect))
    pinn_body<true>(sm, timeP, powerP, W0, b0, b1, b2, lam_m, lam_d, lam_b, bwi,
                    W1s, outP);
  else
    pinn_body<false>(sm, timeP, powerP, W0, b0, b1, b2, lam_m, lam_d, lam_b, bwi,
                     W1s, outP);
}

extern "C" void kernel_launch(void* const* d_in, const int* in_sizes, int n_in,
                              void* d_out, int out_size, void* d_ws, size_t ws_size,
                              hipStream_t stream) {
  const void* timeP  = d_in[0];
  const void* powerP = d_in[1];
  const void* W0     = d_in[2];
  const void* b0     = d_in[3];
  const void* W1     = d_in[4];
  const void* b1     = d_in[5];
  const void* W2     = d_in[6];
  const void* b2     = d_in[7];
  const void* lam_m  = d_in[8];
  const void* lam_d  = d_in[9];
  const void* lam_b  = d_in[10];
  const void* bwi    = d_in[11];

  ushort* W1s = (ushort*)d_ws;            // W1 frags 128 KB; W2 frags at +65536
  ushort* W2s = W1s + H * H;

  swz_kernel<<<288, 256, 0, stream>>>(W1, W2, W1s, W2s);
  pinn_kernel<<<1024, 256, 0, stream>>>(timeP, powerP, W0, b0, b1, b2,
                                        lam_m, lam_d, lam_b, bwi, W1,
                                        W1s, d_out);
  (void)W2s;
}

// Round 5
// 143.519 us; speedup vs baseline: 1.3671x; 1.3671x over previous
//
#include <hip/hip_runtime.h>

#define NPTS 65536
#define NB 32
#define H 256
#define K2E 2.8853900817779268f   // 2*log2(e): tanh(z)=1-2/(exp2(K2E*z)+1)

typedef __attribute__((ext_vector_type(8))) short bhalf8;   // 8 bf16 = 4 VGPRs
typedef __attribute__((ext_vector_type(4))) float f32x4;

union BHU { bhalf8 h; uint u[4]; };

__device__ __forceinline__ float bf2f(ushort u) {
  union { uint x; float f; } c; c.x = ((uint)u) << 16; return c.f;
}
__device__ __forceinline__ ushort f2bf(float f) {            // RNE (final outputs only)
  uint x = __float_as_uint(f);
  uint r = x + 0x7FFFu + ((x >> 16) & 1u);
  return (ushort)(r >> 16);
}
__device__ __forceinline__ uint packrne(float a, float b) {
  return (uint)f2bf(a) | ((uint)f2bf(b) << 16);
}
// truncating bf16 — MFMA inputs / LDS intermediates only
__device__ __forceinline__ ushort trunc1(float f) {
  return (ushort)(__float_as_uint(f) >> 16);
}
__device__ __forceinline__ uint packtr(float a, float b) {
  return (__float_as_uint(a) >> 16) | (__float_as_uint(b) & 0xFFFF0000u);
}
// tanh with pre-folded 2*log2e arg: v_exp + v_add + v_rcp + v_fma
__device__ __forceinline__ float tanh_pf(float z2e) {
  float e = exp2f(z2e);
  float r = __builtin_amdgcn_rcpf(e + 1.0f);
  return fmaf(-2.0f, r, 1.0f);
}

// dtype detect from W1 bit pattern (wave-uniform)
__device__ __forceinline__ bool detect_bf16(const void* W1) {
  const uint4* p = (const uint4*)W1;
  int cnt = 0;
#pragma unroll
  for (int i = 0; i < 8; i++) {
    uint4 v = p[i];
    uint d[4] = {v.x, v.y, v.z, v.w};
#pragma unroll
    for (int k = 0; k < 4; k++) {
      int e = (d[k] >> 7) & 0xFF;                 // exponent of low halfword
      cnt += (e >= 0x70 && e <= 0x7E) ? 1 : 0;
    }
  }
  return cnt >= 16;
}

template<bool B16> __device__ __forceinline__ float LD(const void* p, int i) {
  if constexpr (B16) return bf2f(((const ushort*)p)[i]);
  else               return ((const float*)p)[i];
}
template<bool B16> __device__ __forceinline__ void ST(void* p, int i, float v) {
  if constexpr (B16) ((ushort*)p)[i] = f2bf(v);
  else               ((float*)p)[i] = v;
}

// Pre-swizzle W1 [256][256], W2 [256][32] into MFMA B-frag order (bf16):
// frag(ct,kk): lane l=q*16+r holds B[kk*32+q*8+j][ct*16+r], j=0..7.
__global__ void swz_kernel(const void* W1, const void* W2,
                           ushort* __restrict__ W1s, ushort* __restrict__ W2s) {
  int gid = blockIdx.x * 256 + threadIdx.x;
  bool b16 = detect_bf16(W1);
  if (gid < 65536) {
    int r = gid & 15, q = (gid >> 4) & 3, j = (gid >> 6) & 7;
    int kk = (gid >> 9) & 7, ct = gid >> 12;
    int src = (kk * 32 + q * 8 + j) * H + ct * 16 + r;
    int dst = ((ct * 8 + kk) * 64 + q * 16 + r) * 8 + j;
    float v = b16 ? bf2f(((const ushort*)W1)[src]) : ((const float*)W1)[src];
    W1s[dst] = f2bf(v);
  } else {
    int g2 = gid - 65536;
    int r = g2 & 15, q = (g2 >> 4) & 3, j = (g2 >> 6) & 7;
    int kk = (g2 >> 9) & 7, ct = (g2 >> 12) & 1;
    int src = (kk * 32 + q * 8 + j) * NB + ct * 16 + r;
    int dst = ((ct * 8 + kk) * 64 + q * 16 + r) * 8 + j;
    float v = b16 ? bf2f(((const ushort*)W2)[src]) : ((const float*)W2)[src];
    W2s[dst] = f2bf(v);
  }
}

#define PPITCH 40    // bf16 cols: 80B rows, b128-aligned
#define PSP 17       // psum padded row stride (floats) — breaks bank aliasing

// LDS 40576 B <= 40KB -> 4 blocks/CU. Block = 4 waves = 2 tiles x 2 K-half waves.
//   pairw: per-TILE h1 chunk (shared by its wave pair; sin/cos reuse in epilogue)
//   w1st : 2-buffer ring of one-ct W1 B-frag chunks (global_load_lds, linear)
//   u    : A-build constants (pre-loop) OVERLAID with psum exchange (in-loop)
struct Smem {
  alignas(16) ushort pairw[2][48 * PPITCH];        //  7680 B
  alignas(16) ushort w1st[2][4096];                // 16384 B
  alignas(16) ushort lamTf[2 * 64 * 8];            //  2048 B
  union U {
    struct { float w0d[H], w0e[H], b0e[H]; } c;    //  3072 B (A-build only)
    float psum[2 * 2 * 3 * 16 * PSP];              // 13056 B [tile][h][ch][row][PSP]
  } u;
  alignas(16) float b1e[H];                        //  1024 B
  alignas(16) float b2c[NB], lamMc[NB], lamDc[NB]; //   384 B
};                                                 // 40576 B

// Stage one ct's 8KB W1-frag chunk into an LDS ring buffer (all 4 waves help).
__device__ __forceinline__ void stage_ct(const ushort* __restrict__ W1s,
                                         ushort* buf, int ct, int wave, int lane) {
#pragma unroll
  for (int c = 0; c < 2; c++) {
    const ushort* src = W1s + ct * 4096 + (wave * 2 + c) * 512 + lane * 8;
    ushort* dst = buf + (wave * 2 + c) * 512;   // wave-uniform
    __builtin_amdgcn_global_load_lds(
        (const __attribute__((address_space(1))) unsigned int*)src,
        (__attribute__((address_space(3))) unsigned int*)dst, 16, 0, 0);
  }
}

#define MFMA16(a, b, c) __builtin_amdgcn_mfma_f32_16x16x32_bf16(a, b, c, 0, 0, 0)

// Half-K GEMM1: 4 frags (K=128), 12 MFMA. fb = (4h)*64 + lane.
__device__ __forceinline__ void gemm1h(const ushort* __restrict__ buf, int fb,
                                       const bhalf8* a0f, const bhalf8* a1f,
                                       const bhalf8* a2f,
                                       f32x4& c0, f32x4& c1, f32x4& c2) {
  f32x4 z = {0.f, 0.f, 0.f, 0.f};
  c0 = z; c1 = z; c2 = z;
  const bhalf8* bp = (const bhalf8*)buf + fb;
  bhalf8 bx = bp[0], by = bp[64];
#pragma unroll
  for (int kl = 0; kl < 4; kl += 2) {
    __builtin_amdgcn_s_setprio(1);
    c0 = MFMA16(a0f[kl], bx, c0);
    c1 = MFMA16(a1f[kl], bx, c1);
    c2 = MFMA16(a2f[kl], bx, c2);
    __builtin_amdgcn_s_setprio(0);
    if (kl < 2) bx = bp[2 * 64];
    __builtin_amdgcn_s_setprio(1);
    c0 = MFMA16(a0f[kl + 1], by, c0);
    c1 = MFMA16(a1f[kl + 1], by, c1);
    c2 = MFMA16(a2f[kl + 1], by, c2);
    __builtin_amdgcn_s_setprio(0);
    if (kl < 2) by = bp[3 * 64];
  }
}

template<bool B16>
__device__ void pinn_body(Smem& sm,
                          const void* timeP, const void* powerP,
                          const void* W0, const void* b0,
                          const void* b1, const void* b2,
                          const void* lam_m, const void* lam_d,
                          const void* lam_b, const void* bwi,
                          const ushort* __restrict__ W1s, void* outP) {
  const int tid = threadIdx.x;
  const int wave = tid >> 6, lane = tid & 63;
  const int q = lane >> 4, r = lane & 15;
  const int tile = wave >> 1, h = wave & 1;     // K-half this wave owns
  const ushort* W2s = W1s + H * H;

  stage_ct(W1s, &sm.w1st[0][0], 0, wave, lane);  // prologue stage, hides under preamble

  // ================= preamble =================
  if (tid < 128) {   // lambda^T B-frags: lane holds lam_b[ct*16+r][q*8+j]
    int ct = tid >> 6, l2 = tid & 63, qq = l2 >> 4, rr = l2 & 15;
    BHU t;
#pragma unroll
    for (int j = 0; j < 8; j += 2)
      t.u[j >> 1] = packrne(LD<B16>(lam_b, (ct * 16 + rr) * NB + qq * 8 + j),
                            LD<B16>(lam_b, (ct * 16 + rr) * NB + qq * 8 + j + 1));
    *(bhalf8*)(sm.lamTf + tid * 8) = t.h;
  }
  if (tid < H) {
    float w0v = LD<B16>(W0, tid);
    sm.u.c.w0d[tid] = 0.1f * w0v;      // pre-fold 2/TMAX chain-rule factor
    sm.u.c.w0e[tid] = K2E * w0v;
    sm.u.c.b0e[tid] = K2E * LD<B16>(b0, tid);
    sm.b1e[tid] = K2E * LD<B16>(b1, tid);
  }
  if (tid < NB) {
    sm.b2c[tid]   = LD<B16>(b2, tid);
    sm.lamMc[tid] = LD<B16>(lam_m, tid) * LD<B16>(bwi, tid);
    sm.lamDc[tid] = LD<B16>(lam_d, tid);
  }
  __syncthreads();

  // ================= per-tile / per-half-K setup =================
  const int s0 = (blockIdx.x * 2 + tile) * 16;
  ushort* pw = &sm.pairw[tile][0];
  float* ps = sm.u.psum + (tile * 2 + h) * (3 * 16 * PSP);
  const float* pa = sm.u.psum + (tile * 2 + 0) * (3 * 16 * PSP);
  const float* pb = sm.u.psum + (tile * 2 + 1) * (3 * 16 * PSP);
  const int fb = (4 * h) * 64 + lane;

  float t = LD<B16>(timeP, s0 + r);
  float x = t * 0.1f - 1.0f;               // 2t/TMAX - 1, TMAX = 20

  // ---- A-frags for THIS K-half only: 3 chains x 4 frags = 48 VGPRs ----
  bhalf8 a0f[4], a1f[4], a2f[4];
#pragma unroll
  for (int kl = 0; kl < 4; kl++) {
    int kk = 4 * h + kl;
    BHU t0, t1, t2;
#pragma unroll
    for (int h4 = 0; h4 < 2; h4++) {
      int k0 = kk * 32 + q * 8 + h4 * 4;
      float4 wv4 = *(const float4*)&sm.u.c.w0d[k0];
      float4 ev4 = *(const float4*)&sm.u.c.w0e[k0];
      float4 bv4 = *(const float4*)&sm.u.c.b0e[k0];
      float wv[4] = {wv4.x, wv4.y, wv4.z, wv4.w};
      float ev[4] = {ev4.x, ev4.y, ev4.z, ev4.w};
      float bv[4] = {bv4.x, bv4.y, bv4.z, bv4.w};
      float vv[4], d1v[4], d2v[4];
#pragma unroll
      for (int j = 0; j < 4; j++) {
        float v = tanh_pf(fmaf(x, ev[j], bv[j]));
        float s2 = 1.0f - v * v;
        vv[j] = v; d1v[j] = s2 * wv[j]; d2v[j] = -2.0f * v * d1v[j] * wv[j];
      }
      t0.u[h4 * 2 + 0] = packtr(vv[0], vv[1]); t0.u[h4 * 2 + 1] = packtr(vv[2], vv[3]);
      t1.u[h4 * 2 + 0] = packtr(d1v[0], d1v[1]); t1.u[h4 * 2 + 1] = packtr(d1v[2], d1v[3]);
      t2.u[h4 * 2 + 0] = packtr(d2v[0], d2v[1]); t2.u[h4 * 2 + 1] = packtr(d2v[2], d2v[3]);
    }
    a0f[kl] = t0.h; a1f[kl] = t1.h; a2f[kl] = t2.h;
  }

  // ---- main loop: barrier1 (vmcnt+lgkm drain: pw/psum now CROSS-WAVE) ->
  //      stage -> half-GEMM1 -> [w2 load | GEMM2] -> psum publish ->
  //      barrier2 (lgkm) -> sum halves + chain (2 rows/thread) ----
  f32x4 acc2[3];
  { f32x4 z = {0.f,0.f,0.f,0.f}; acc2[0] = z; acc2[1] = z; acc2[2] = z; }
  bhalf8 w2f = {};

#pragma unroll 1
  for (int ct = 0; ct < 16; ++ct) {
    asm volatile("s_waitcnt vmcnt(0) lgkmcnt(0)\n\ts_barrier" ::: "memory");

    if (ct < 15) stage_ct(W1s, &sm.w1st[(ct + 1) & 1][0], ct + 1, wave, lane);

    f32x4 c0, c1, c2;
    gemm1h(&sm.w1st[ct & 1][0], fb, a0f, a1f, a2f, c0, c1, c2);

    if (ct & 1) {
      int pp = ct >> 1;   // W2 frag for pair pp, consumed at ct+1 (and tail)
      w2f = *(const bhalf8*)(W2s + ((h * 8 + pp) * 64 + lane) * 8);
    } else if (ct >= 2) {
      // GEMM2 pair ct/2-1: reads pw (completed pair) BEFORE this ct's chain writes
      bhalf8 hf = *(const bhalf8*)(pw + (0 * 16 + r) * PPITCH + q * 8);
      acc2[0] = MFMA16(hf, w2f, acc2[0]);
      hf = *(const bhalf8*)(pw + (1 * 16 + r) * PPITCH + q * 8);
      acc2[1] = MFMA16(hf, w2f, acc2[1]);
      hf = *(const bhalf8*)(pw + (2 * 16 + r) * PPITCH + q * 8);
      acc2[2] = MFMA16(hf, w2f, acc2[2]);
    }

    // publish this half's partial C fragment (f32, padded stride)
#pragma unroll
    for (int i = 0; i < 4; i++) {
      int ro = (q * 4 + i) * PSP + r;
      ps[0 * 16 * PSP + ro] = c0[i];
      ps[1 * 16 * PSP + ro] = c1[i];
      ps[2 * 16 * PSP + ro] = c2[i];
    }
    asm volatile("s_waitcnt lgkmcnt(0)\n\ts_barrier" ::: "memory");

    {
      float b1v = sm.b1e[ct * 16 + r];
      int lc = ((ct & 1) << 4) + r;
      int rb = 8 * h + 2 * q;          // this wave chains rows [8h, 8h+8)
#pragma unroll
      for (int d = 0; d < 2; d++) {
        int rr = rb + d;
        int ro = rr * PSP + r;
        float f0 = pa[0 * 16 * PSP + ro] + pb[0 * 16 * PSP + ro];
        float f1 = pa[1 * 16 * PSP + ro] + pb[1 * 16 * PSP + ro];
        float f2 = pa[2 * 16 * PSP + ro] + pb[2 * 16 * PSP + ro];
        float hv  = tanh_pf(fmaf(f0, K2E, b1v));
        float s2  = 1.0f - hv * hv;
        float hd  = s2 * f1;
        float hdd = s2 * f2 - 2.0f * hv * hd * f1;
        pw[rr * PPITCH + lc]        = trunc1(hv);
        pw[(16 + rr) * PPITCH + lc] = trunc1(hd);
        pw[(32 + rr) * PPITCH + lc] = trunc1(hdd);
      }
    }
  }

  // ---- tail GEMM2 (pair 7) — chain(15) writes must be visible ----
  asm volatile("s_waitcnt lgkmcnt(0)\n\ts_barrier" ::: "memory");
  {
    bhalf8 hf = *(const bhalf8*)(pw + (0 * 16 + r) * PPITCH + q * 8);
    acc2[0] = MFMA16(hf, w2f, acc2[0]);
    hf = *(const bhalf8*)(pw + (1 * 16 + r) * PPITCH + q * 8);
    acc2[1] = MFMA16(hf, w2f, acc2[1]);
    hf = *(const bhalf8*)(pw + (2 * 16 + r) * PPITCH + q * 8);
    acc2[2] = MFMA16(hf, w2f, acc2[2]);
  }
  // all waves' tail reads drained before sin/cos overwrite pw
  asm volatile("s_waitcnt lgkmcnt(0)\n\ts_barrier" ::: "memory");

  // ---- epilogue: this wave owns bus block b = h*16 + r ----
  const int b = h * 16 + r;
  float b2v = sm.b2c[b], lm = sm.lamMc[b], ldv = sm.lamDc[b];
  float dv[4], dtv[4], dtt[4], sn[4], cs[4], Pv[4];
#pragma unroll
  for (int i = 0; i < 4; i++) {
    int n = s0 + q * 4 + i;
    Pv[i]  = LD<B16>(powerP, n * NB + b);
    dv[i]  = acc2[0][i] + b2v;
    dtv[i] = acc2[1][i];
    dtt[i] = acc2[2][i];
    __sincosf(dv[i], &sn[i], &cs[i]);
    pw[(q * 4 + i) * PPITCH + b]      = trunc1(sn[i]);   // rows 0..15: sin
    pw[(16 + q * 4 + i) * PPITCH + b] = trunc1(cs[i]);   // rows 16..31: cos
    ST<B16>(outP, n * NB + b, dv[i]);
    ST<B16>(outP, NPTS * NB + n * NB + b, dtv[i]);
  }
  asm volatile("s_waitcnt lgkmcnt(0)\n\ts_barrier" ::: "memory");

  // coupling: C = cos @ lam^T, S = sin @ lam^T; each wave does its c2=h block
  bhalf8 snA = *(const bhalf8*)(pw + r * PPITCH + q * 8);
  bhalf8 csA = *(const bhalf8*)(pw + (16 + r) * PPITCH + q * 8);
  bhalf8 lt  = *(const bhalf8*)(sm.lamTf + (h * 64 + lane) * 8);
  f32x4 z = {0.f,0.f,0.f,0.f};
  f32x4 accC = MFMA16(csA, lt, z);
  f32x4 accS = MFMA16(snA, lt, z);
#pragma unroll
  for (int i = 0; i < 4; i++) {
    float conn = sn[i] * accC[i] - cs[i] * accS[i];
    float phys = lm * dtt[i] + ldv * dtv[i] + conn - Pv[i];
    int n = s0 + q * 4 + i;
    ST<B16>(outP, 2 * NPTS * NB + n * NB + b, phys);
  }
}

// (256,4): K-split halves the persistent state (a-frags 96->48, acc2 24->12,
// w2 8->4) -> est. peak ~104 total regs, REAL margin under the 128-band cap
// (rounds 2/4 proved the old structure's 140-reg set spills at this cap).
// Go/no-go: WRITE_SIZE ~24.5MB & FETCH ~5MB = no spill.
__global__ __launch_bounds__(256, 4)
void pinn_kernel(const void* timeP, const void* powerP,
                 const void* W0, const void* b0,
                 const void* b1, const void* b2,
                 const void* lam_m, const void* lam_d,
                 const void* lam_b, const void* bwi,
                 const void* W1_for_detect,
                 const ushort* __restrict__ W1s, void* outP) {
  __shared__ Smem sm;
  if (detect_bf16(W1_for_detect))
    pinn_body<true>(sm, timeP, powerP, W0, b0, b1, b2, lam_m, lam_d, lam_b, bwi,
                    W1s, outP);
  else
    pinn_body<false>(sm, timeP, powerP, W0, b0, b1, b2, lam_m, lam_d, lam_b, bwi,
                     W1s, outP);
}

extern "C" void kernel_launch(void* const* d_in, const int* in_sizes, int n_in,
                              void* d_out, int out_size, void* d_ws, size_t ws_size,
                              hipStream_t stream) {
  const void* timeP  = d_in[0];
  const void* powerP = d_in[1];
  const void* W0     = d_in[2];
  const void* b0     = d_in[3];
  const void* W1     = d_in[4];
  const void* b1     = d_in[5];
  const void* W2     = d_in[6];
  const void* b2     = d_in[7];
  const void* lam_m  = d_in[8];
  const void* lam_d  = d_in[9];
  const void* lam_b  = d_in[10];
  const void* bwi    = d_in[11];

  ushort* W1s = (ushort*)d_ws;            // W1 frags 128 KB; W2 frags at +65536
  ushort* W2s = W1s + H * H;

  swz_kernel<<<288, 256, 0, stream>>>(W1, W2, W1s, W2s);
  pinn_kernel<<<2048, 256, 0, stream>>>(timeP, powerP, W0, b0, b1, b2,
                                        lam_m, lam_d, lam_b, bwi, W1,
                                        W1s, d_out);
  (void)W2s;
}

// Round 7
// 134.286 us; speedup vs baseline: 1.4611x; 1.0688x over previous
//
#include <hip/hip_runtime.h>

#define NPTS 65536
#define NB 32
#define H 256
#define K2E 2.8853900817779268f   // 2*log2(e): tanh(z)=1-2/(exp2(K2E*z)+1)

typedef __attribute__((ext_vector_type(8))) short bhalf8;   // 8 bf16 = 4 VGPRs
typedef __attribute__((ext_vector_type(4))) float f32x4;

union BHU { bhalf8 h; uint u[4]; };

__device__ __forceinline__ float bf2f(ushort u) {
  union { uint x; float f; } c; c.x = ((uint)u) << 16; return c.f;
}
__device__ __forceinline__ ushort f2bf(float f) {            // RNE (final outputs only)
  uint x = __float_as_uint(f);
  uint r = x + 0x7FFFu + ((x >> 16) & 1u);
  return (ushort)(r >> 16);
}
__device__ __forceinline__ uint packrne(float a, float b) {
  return (uint)f2bf(a) | ((uint)f2bf(b) << 16);
}
// truncating bf16 — MFMA inputs / LDS intermediates only
__device__ __forceinline__ ushort trunc1(float f) {
  return (ushort)(__float_as_uint(f) >> 16);
}
__device__ __forceinline__ uint packtr(float a, float b) {
  return (__float_as_uint(a) >> 16) | (__float_as_uint(b) & 0xFFFF0000u);
}
// tanh with pre-folded 2*log2e arg: v_exp + v_add + v_rcp + v_fma
__device__ __forceinline__ float tanh_pf(float z2e) {
  float e = exp2f(z2e);
  float r = __builtin_amdgcn_rcpf(e + 1.0f);
  return fmaf(-2.0f, r, 1.0f);
}

// dtype detect from W1 bit pattern (wave-uniform)
__device__ __forceinline__ bool detect_bf16(const void* W1) {
  const uint4* p = (const uint4*)W1;
  int cnt = 0;
#pragma unroll
  for (int i = 0; i < 8; i++) {
    uint4 v = p[i];
    uint d[4] = {v.x, v.y, v.z, v.w};
#pragma unroll
    for (int k = 0; k < 4; k++) {
      int e = (d[k] >> 7) & 0xFF;                 // exponent of low halfword
      cnt += (e >= 0x70 && e <= 0x7E) ? 1 : 0;
    }
  }
  return cnt >= 16;
}

template<bool B16> __device__ __forceinline__ float LD(const void* p, int i) {
  if constexpr (B16) return bf2f(((const ushort*)p)[i]);
  else               return ((const float*)p)[i];
}
template<bool B16> __device__ __forceinline__ void ST(void* p, int i, float v) {
  if constexpr (B16) ((ushort*)p)[i] = f2bf(v);
  else               ((float*)p)[i] = v;
}

// Pre-swizzle W1 [256][256], W2 [256][32] into MFMA B-frag order (bf16):
// frag(ct,kk): lane l=q*16+r holds B[kk*32+q*8+j][ct*16+r], j=0..7.
__global__ void swz_kernel(const void* W1, const void* W2,
                           ushort* __restrict__ W1s, ushort* __restrict__ W2s) {
  int gid = blockIdx.x * 256 + threadIdx.x;
  bool b16 = detect_bf16(W1);
  if (gid < 65536) {
    int r = gid & 15, q = (gid >> 4) & 3, j = (gid >> 6) & 7;
    int kk = (gid >> 9) & 7, ct = gid >> 12;
    int src = (kk * 32 + q * 8 + j) * H + ct * 16 + r;
    int dst = ((ct * 8 + kk) * 64 + q * 16 + r) * 8 + j;
    float v = b16 ? bf2f(((const ushort*)W1)[src]) : ((const float*)W1)[src];
    W1s[dst] = f2bf(v);
  } else {
    int g2 = gid - 65536;
    int r = g2 & 15, q = (g2 >> 4) & 3, j = (g2 >> 6) & 7;
    int kk = (g2 >> 9) & 7, ct = (g2 >> 12) & 1;
    int src = (kk * 32 + q * 8 + j) * NB + ct * 16 + r;
    int dst = ((ct * 8 + kk) * 64 + q * 16 + r) * 8 + j;
    float v = b16 ? bf2f(((const ushort*)W2)[src]) : ((const float*)W2)[src];
    W2s[dst] = f2bf(v);
  }
}

#define PPITCH 40    // bf16 cols: 80B rows, b128-aligned

// LDS 62848 B. NO cross-wave coupling in the main loop: each wave owns a
// private 3-slot x 2KB W1 ring (global_load_lds, per-wave counted vmcnt —
// no s_barrier after the preamble). W2 frags staged once into shared W2l so
// the in-loop vmcnt stream is PURE ring stages (exact counting).
struct Smem {
  alignas(16) ushort pairw[4][48 * PPITCH];  // 15360 B wave-private h1 chunk
  alignas(16) ushort ring[4][3 * 1024];      // 24576 B wave-private W1 rings
  alignas(16) ushort W2l[16 * 64 * 8];       // 16384 B W2 B-frags (shared, RO)
  alignas(16) ushort lamTf[2 * 64 * 8];      //  2048 B lambda^T B-frags
  alignas(16) float  w0d[H], w0e[H], b0e[H], b1e[H]; // 4096 B
  alignas(16) float  b2c[NB], lamMc[NB], lamDc[NB]; // 384 B
};

// Stage one 2KB chunk (2 frags) of W1s into this wave's ring slot. 2 issues.
__device__ __forceinline__ void stage_chunk(const ushort* __restrict__ W1s,
                                            ushort* dst, int s, int lane) {
#pragma unroll
  for (int c = 0; c < 2; c++) {
    const ushort* src = W1s + s * 1024 + c * 512 + lane * 8;
    __builtin_amdgcn_global_load_lds(
        (const __attribute__((address_space(1))) unsigned int*)src,
        (__attribute__((address_space(3))) unsigned int*)(dst + c * 512), 16, 0, 0);
  }
}

#define MFMA16(a, b, c) __builtin_amdgcn_mfma_f32_16x16x32_bf16(a, b, c, 0, 0, 0)

// tanh chain for one ct -> pw column lc
__device__ __forceinline__ void chain(ushort* pw, float b1v, int q, int lc,
                                      const f32x4& c0, const f32x4& c1,
                                      const f32x4& c2) {
#pragma unroll
  for (int i = 0; i < 4; i++) {
    float hv  = tanh_pf(fmaf(c0[i], K2E, b1v));
    float s2  = 1.0f - hv * hv;
    float hd  = s2 * c1[i];
    float hdd = s2 * c2[i] - 2.0f * hv * hd * c1[i];
    int row = q * 4 + i;
    pw[row * PPITCH + lc]        = trunc1(hv);
    pw[(16 + row) * PPITCH + lc] = trunc1(hd);
    pw[(32 + row) * PPITCH + lc] = trunc1(hdd);
  }
}

template<bool B16>
__device__ void pinn_body(Smem& sm,
                          const void* timeP, const void* powerP,
                          const void* W0, const void* b0,
                          const void* b1, const void* b2,
                          const void* lam_m, const void* lam_d,
                          const void* lam_b, const void* bwi,
                          const ushort* __restrict__ W1s, void* outP) {
  const int tid = threadIdx.x;
  const int wave = tid >> 6, lane = tid & 63;
  const int q = lane >> 4, r = lane & 15;
  const ushort* W2s = W1s + H * H;
  ushort* rb = &sm.ring[wave][0];

  // prologue stages (all drained by the preamble __syncthreads):
  // ring chunks 0,1,2 -> slots 0,1,2 (wave-private)
  stage_chunk(W1s, rb + 0 * 1024, 0, lane);
  stage_chunk(W1s, rb + 1 * 1024, 1, lane);
  stage_chunk(W1s, rb + 2 * 1024, 2, lane);
  // W2 frag table -> shared W2l (each wave copies 4 x 1KB, linear)
#pragma unroll
  for (int c = 0; c < 4; c++) {
    const ushort* src = W2s + (wave * 4 + c) * 512 + lane * 8;
    __builtin_amdgcn_global_load_lds(
        (const __attribute__((address_space(1))) unsigned int*)src,
        (__attribute__((address_space(3))) unsigned int*)(sm.W2l + (wave * 4 + c) * 512),
        16, 0, 0);
  }

  // ================= preamble (the ONLY barrier) =================
  if (tid < 128) {   // lambda^T B-frags: lane holds lam_b[ct*16+r][q*8+j]
    int ct = tid >> 6, l2 = tid & 63, qq = l2 >> 4, rr = l2 & 15;
    BHU t;
#pragma unroll
    for (int j = 0; j < 8; j += 2)
      t.u[j >> 1] = packrne(LD<B16>(lam_b, (ct * 16 + rr) * NB + qq * 8 + j),
                            LD<B16>(lam_b, (ct * 16 + rr) * NB + qq * 8 + j + 1));
    *(bhalf8*)(sm.lamTf + tid * 8) = t.h;
  }
  if (tid < H) {
    float w0v = LD<B16>(W0, tid);
    sm.w0d[tid] = 0.1f * w0v;          // pre-fold 2/TMAX chain-rule factor
    sm.w0e[tid] = K2E * w0v;
    sm.b0e[tid] = K2E * LD<B16>(b0, tid);
    sm.b1e[tid] = K2E * LD<B16>(b1, tid);
  }
  if (tid < NB) {
    sm.b2c[tid]   = LD<B16>(b2, tid);
    sm.lamMc[tid] = LD<B16>(lam_m, tid) * LD<B16>(bwi, tid);
    sm.lamDc[tid] = LD<B16>(lam_d, tid);
  }
  __syncthreads();   // drains all prologue stages too (vmcnt(0) before barrier)

  // ================= per-wave sample tile =================
  const int s0 = (blockIdx.x * 4 + wave) * 16;
  ushort* pw = &sm.pairw[wave][0];

  float t = LD<B16>(timeP, s0 + r);
  float x = t * 0.1f - 1.0f;               // 2t/TMAX - 1, TMAX = 20

  // ---- A-frags in registers: lane holds Ach[r][kk*32+q*8+j] ----
  bhalf8 a0f[8], a1f[8], a2f[8];
#pragma unroll
  for (int kk = 0; kk < 8; kk++) {
    BHU t0, t1, t2;
#pragma unroll
    for (int h = 0; h < 2; h++) {
      int k0 = kk * 32 + q * 8 + h * 4;
      float4 wv4 = *(const float4*)&sm.w0d[k0];
      float4 ev4 = *(const float4*)&sm.w0e[k0];
      float4 bv4 = *(const float4*)&sm.b0e[k0];
      float wv[4] = {wv4.x, wv4.y, wv4.z, wv4.w};
      float ev[4] = {ev4.x, ev4.y, ev4.z, ev4.w};
      float bv[4] = {bv4.x, bv4.y, bv4.z, bv4.w};
      float vv[4], d1v[4], d2v[4];
#pragma unroll
      for (int j = 0; j < 4; j++) {
        float v = tanh_pf(fmaf(x, ev[j], bv[j]));
        float s2 = 1.0f - v * v;
        vv[j] = v; d1v[j] = s2 * wv[j]; d2v[j] = -2.0f * v * d1v[j] * wv[j];
      }
      t0.u[h * 2 + 0] = packtr(vv[0], vv[1]); t0.u[h * 2 + 1] = packtr(vv[2], vv[3]);
      t1.u[h * 2 + 0] = packtr(d1v[0], d1v[1]); t1.u[h * 2 + 1] = packtr(d1v[2], d1v[3]);
      t2.u[h * 2 + 0] = packtr(d2v[0], d2v[1]); t2.u[h * 2 + 1] = packtr(d2v[2], d2v[3]);
    }
    a0f[kk] = t0.h; a1f[kk] = t1.h; a2f[kk] = t2.h;
  }

  // ---- main loop: BARRIER-FREE. Per 2KB chunk: wait vmcnt(4) [own ring,
  // counted: chunks s+1,s+2 stay in flight], 2 ds_read_b128, lgkmcnt(0)+
  // sched_barrier (WAR guard: reads complete before in-slot restage), restage
  // chunk (s+3)&63 into the same slot, 6 MFMA. Staging is UNCONDITIONAL with
  // wrap — round-6 bug: tail special-case broke the vmcnt ledger (at ct=15
  // c4>=1 outstanding dropped to 4, vmcnt(4) no-op'd, chunks 62/63 were read
  // before retirement -> absmax 0.70). Wrap keeps outstanding = 6 before
  // every wait so vmcnt(4) always retires exactly the chunk being read; the
  // 3 wrap-stages land after their slot's final read (read precedes stage)
  // and are never consumed. Waves free-run and desync -> cross-wave
  // MFMA/VALU overlap (m114) covers the chain latency.
  f32x4 acc2[3][2];
#pragma unroll
  for (int ch = 0; ch < 3; ch++)
#pragma unroll
    for (int c2i = 0; c2i < 2; c2i++) { f32x4 z = {0.f,0.f,0.f,0.f}; acc2[ch][c2i] = z; }

  bhalf8 w2f0 = {}, w2f1 = {};
  int slot = 0;

#pragma unroll 1
  for (int ct = 0; ct < 16; ++ct) {
    f32x4 c0 = {0.f,0.f,0.f,0.f}, c1 = c0, c2 = c0;
#pragma unroll
    for (int c4 = 0; c4 < 4; ++c4) {
      asm volatile("s_waitcnt vmcnt(4)" ::: "memory");
      bhalf8 bx = *(const bhalf8*)(rb + slot * 1024 + lane * 8);
      bhalf8 by = *(const bhalf8*)(rb + slot * 1024 + 512 + lane * 8);
      asm volatile("s_waitcnt lgkmcnt(0)" ::: "memory");
      __builtin_amdgcn_sched_barrier(0);
      stage_chunk(W1s, rb + slot * 1024, (ct * 4 + c4 + 3) & 63, lane);
      __builtin_amdgcn_s_setprio(1);
      c0 = MFMA16(a0f[2 * c4], bx, c0);
      c1 = MFMA16(a1f[2 * c4], bx, c1);
      c2 = MFMA16(a2f[2 * c4], bx, c2);
      c0 = MFMA16(a0f[2 * c4 + 1], by, c0);
      c1 = MFMA16(a1f[2 * c4 + 1], by, c1);
      c2 = MFMA16(a2f[2 * c4 + 1], by, c2);
      __builtin_amdgcn_s_setprio(0);
      slot = (slot == 2) ? 0 : slot + 1;
    }

    if (ct & 1) {
      int pp = ct >> 1;   // W2 frags (LDS) for pair pp, consumed at ct+1 / tail
      w2f0 = *(const bhalf8*)(sm.W2l + ((0 * 8 + pp) * 64 + lane) * 8);
      w2f1 = *(const bhalf8*)(sm.W2l + ((1 * 8 + pp) * 64 + lane) * 8);
    } else if (ct >= 2) {
      // GEMM2 pair ct/2-1: reads pw BEFORE this ct's chain overwrites cols 0..15
      bhalf8 hf = *(const bhalf8*)(pw + (0 * 16 + r) * PPITCH + q * 8);
      acc2[0][0] = MFMA16(hf, w2f0, acc2[0][0]);
      acc2[0][1] = MFMA16(hf, w2f1, acc2[0][1]);
      hf = *(const bhalf8*)(pw + (1 * 16 + r) * PPITCH + q * 8);
      acc2[1][0] = MFMA16(hf, w2f0, acc2[1][0]);
      acc2[1][1] = MFMA16(hf, w2f1, acc2[1][1]);
      hf = *(const bhalf8*)(pw + (2 * 16 + r) * PPITCH + q * 8);
      acc2[2][0] = MFMA16(hf, w2f0, acc2[2][0]);
      acc2[2][1] = MFMA16(hf, w2f1, acc2[2][1]);
    }

    chain(pw, sm.b1e[ct * 16 + r], q, ((ct & 1) << 4) + r, c0, c1, c2);
  }
  // tail GEMM2 (pair 7) — w2f loaded at ct=15; same-wave pw deps via lgkm tracking
  {
    bhalf8 hf = *(const bhalf8*)(pw + (0 * 16 + r) * PPITCH + q * 8);
    acc2[0][0] = MFMA16(hf, w2f0, acc2[0][0]);
    acc2[0][1] = MFMA16(hf, w2f1, acc2[0][1]);
    hf = *(const bhalf8*)(pw + (1 * 16 + r) * PPITCH + q * 8);
    acc2[1][0] = MFMA16(hf, w2f0, acc2[1][0]);
    acc2[1][1] = MFMA16(hf, w2f1, acc2[1][1]);
    hf = *(const bhalf8*)(pw + (2 * 16 + r) * PPITCH + q * 8);
    acc2[2][0] = MFMA16(hf, w2f0, acc2[2][0]);
    acc2[2][1] = MFMA16(hf, w2f1, acc2[2][1]);
  }

  // ---- epilogue (wave-private, no barriers) ----
  float dv[2][4], dt[2][4], dtt[2][4], sn[2][4], cs[2][4], Pv[2][4];
#pragma unroll
  for (int c2i = 0; c2i < 2; c2i++) {
    int b = c2i * 16 + r;
    float b2v = sm.b2c[b];
#pragma unroll
    for (int i = 0; i < 4; i++) {
      int n = s0 + q * 4 + i;
      Pv[c2i][i] = LD<B16>(powerP, n * NB + b);
      dv[c2i][i]  = acc2[0][c2i][i] + b2v;
      dt[c2i][i]  = acc2[1][c2i][i];
      dtt[c2i][i] = acc2[2][c2i][i];
      __sincosf(dv[c2i][i], &sn[c2i][i], &cs[c2i][i]);
      pw[(q * 4 + i) * PPITCH + b]      = trunc1(sn[c2i][i]);   // rows 0..15: sin
      pw[(16 + q * 4 + i) * PPITCH + b] = trunc1(cs[c2i][i]);   // rows 16..31: cos
      ST<B16>(outP, n * NB + b, dv[c2i][i]);
      ST<B16>(outP, NPTS * NB + n * NB + b, dt[c2i][i]);
    }
  }
  // coupling: C = cos @ lam^T, S = sin @ lam^T  (16x32 @ 32x32 via 16x16x32 MFMA)
  bhalf8 snA = *(const bhalf8*)(pw + r * PPITCH + q * 8);
  bhalf8 csA = *(const bhalf8*)(pw + (16 + r) * PPITCH + q * 8);
  f32x4 accC[2], accS[2];
#pragma unroll
  for (int c2i = 0; c2i < 2; c2i++) {
    bhalf8 lt = *(const bhalf8*)(sm.lamTf + (c2i * 64 + lane) * 8);
    f32x4 z = {0.f,0.f,0.f,0.f};
    accC[c2i] = MFMA16(csA, lt, z);
    accS[c2i] = MFMA16(snA, lt, z);
  }
#pragma unroll
  for (int c2i = 0; c2i < 2; c2i++) {
    int b = c2i * 16 + r;
    float lm = sm.lamMc[b], ldv = sm.lamDc[b];
#pragma unroll
    for (int i = 0; i < 4; i++) {
      float conn = sn[c2i][i] * accC[c2i][i] - cs[c2i][i] * accS[c2i][i];
      float phys = lm * dtt[c2i][i] + ldv * dt[c2i][i] + conn - Pv[c2i][i];
      int n = s0 + q * 4 + i;
      ST<B16>(outP, 2 * NPTS * NB + n * NB + b, phys);
    }
  }
}

// (256,2): accept 2 waves/SIMD (rounds 2/4 proved the ~140-reg live set
// can't fit the 128 band) and recover dead time by removing ALL main-loop
// barriers instead: wave-private staging + counted per-wave vmcnt.
__global__ __launch_bounds__(256, 2)
void pinn_kernel(const void* timeP, const void* powerP,
                 const void* W0, const void* b0,
                 const void* b1, const void* b2,
                 const void* lam_m, const void* lam_d,
                 const void* lam_b, const void* bwi,
                 const void* W1_for_detect,
                 const ushort* __restrict__ W1s, void* outP) {
  __shared__ Smem sm;
  if (detect_bf16(W1_for_detect))
    pinn_body<true>(sm, timeP, powerP, W0, b0, b1, b2, lam_m, lam_d, lam_b, bwi,
                    W1s, outP);
  else
    pinn_body<false>(sm, timeP, powerP, W0, b0, b1, b2, lam_m, lam_d, lam_b, bwi,
                     W1s, outP);
}

extern "C" void kernel_launch(void* const* d_in, const int* in_sizes, int n_in,
                              void* d_out, int out_size, void* d_ws, size_t ws_size,
                              hipStream_t stream) {
  const void* timeP  = d_in[0];
  const void* powerP = d_in[1];
  const void* W0     = d_in[2];
  const void* b0     = d_in[3];
  const void* W1     = d_in[4];
  const void* b1     = d_in[5];
  const void* W2     = d_in[6];
  const void* b2     = d_in[7];
  const void* lam_m  = d_in[8];
  const void* lam_d  = d_in[9];
  const void* lam_b  = d_in[10];
  const void* bwi    = d_in[11];

  ushort* W1s = (ushort*)d_ws;            // W1 frags 128 KB; W2 frags at +65536
  ushort* W2s = W1s + H * H;

  swz_kernel<<<288, 256, 0, stream>>>(W1, W2, W1s, W2s);
  pinn_kernel<<<1024, 256, 0, stream>>>(timeP, powerP, W0, b0, b1, b2,
                                        lam_m, lam_d, lam_b, bwi, W1,
                                        W1s, d_out);
  (void)W2s;
}

// Round 9
// 127.342 us; speedup vs baseline: 1.5407x; 1.0545x over previous
//
#include <hip/hip_runtime.h>

#define NPTS 65536
#define NB 32
#define H 256
#define K2E 2.8853900817779268f   // 2*log2(e): tanh(z)=1-2/(exp2(K2E*z)+1)

typedef __attribute__((ext_vector_type(8))) short bhalf8;   // 8 bf16 = 4 VGPRs
typedef __attribute__((ext_vector_type(4))) float f32x4;

union BHU { bhalf8 h; uint u[4]; };

__device__ __forceinline__ float bf2f(ushort u) {
  union { uint x; float f; } c; c.x = ((uint)u) << 16; return c.f;
}
__device__ __forceinline__ ushort f2bf(float f) {            // RNE (final outputs only)
  uint x = __float_as_uint(f);
  uint r = x + 0x7FFFu + ((x >> 16) & 1u);
  return (ushort)(r >> 16);
}
__device__ __forceinline__ uint packrne(float a, float b) {
  return (uint)f2bf(a) | ((uint)f2bf(b) << 16);
}
// truncating bf16 — MFMA inputs / LDS intermediates only
__device__ __forceinline__ ushort trunc1(float f) {
  return (ushort)(__float_as_uint(f) >> 16);
}
__device__ __forceinline__ uint packtr(float a, float b) {
  return (__float_as_uint(a) >> 16) | (__float_as_uint(b) & 0xFFFF0000u);
}
// tanh with pre-folded 2*log2e arg: v_exp + v_add + v_rcp + v_fma
__device__ __forceinline__ float tanh_pf(float z2e) {
  float e = exp2f(z2e);
  float r = __builtin_amdgcn_rcpf(e + 1.0f);
  return fmaf(-2.0f, r, 1.0f);
}

// dtype detect from W1 bit pattern (wave-uniform)
__device__ __forceinline__ bool detect_bf16(const void* W1) {
  const uint4* p = (const uint4*)W1;
  int cnt = 0;
#pragma unroll
  for (int i = 0; i < 8; i++) {
    uint4 v = p[i];
    uint d[4] = {v.x, v.y, v.z, v.w};
#pragma unroll
    for (int k = 0; k < 4; k++) {
      int e = (d[k] >> 7) & 0xFF;                 // exponent of low halfword
      cnt += (e >= 0x70 && e <= 0x7E) ? 1 : 0;
    }
  }
  return cnt >= 16;
}

template<bool B16> __device__ __forceinline__ float LD(const void* p, int i) {
  if constexpr (B16) return bf2f(((const ushort*)p)[i]);
  else               return ((const float*)p)[i];
}
template<bool B16> __device__ __forceinline__ void ST(void* p, int i, float v) {
  if constexpr (B16) ((ushort*)p)[i] = f2bf(v);
  else               ((float*)p)[i] = v;
}

// Pre-swizzle W1 [256][256], W2 [256][32] into MFMA B-frag order (bf16):
// frag(ct,kk): lane l=q*16+r holds B[kk*32+q*8+j][ct*16+r], j=0..7.
// Separate kernel (NOT fused/cooperative): round-8 proved cross-XCD W1s
// visibility through grid.sync is unreliable; the dispatch boundary is the
// only verified fence.
__global__ void swz_kernel(const void* W1, const void* W2,
                           ushort* __restrict__ W1s, ushort* __restrict__ W2s) {
  int gid = blockIdx.x * 256 + threadIdx.x;
  bool b16 = detect_bf16(W1);
  if (gid < 65536) {
    int r = gid & 15, q = (gid >> 4) & 3, j = (gid >> 6) & 7;
    int kk = (gid >> 9) & 7, ct = gid >> 12;
    int src = (kk * 32 + q * 8 + j) * H + ct * 16 + r;
    int dst = ((ct * 8 + kk) * 64 + q * 16 + r) * 8 + j;
    float v = b16 ? bf2f(((const ushort*)W1)[src]) : ((const float*)W1)[src];
    W1s[dst] = f2bf(v);
  } else {
    int g2 = gid - 65536;
    int r = g2 & 15, q = (g2 >> 4) & 3, j = (g2 >> 6) & 7;
    int kk = (g2 >> 9) & 7, ct = (g2 >> 12) & 1;
    int src = (kk * 32 + q * 8 + j) * NB + ct * 16 + r;
    int dst = ((ct * 8 + kk) * 64 + q * 16 + r) * 8 + j;
    float v = b16 ? bf2f(((const ushort*)W2)[src]) : ((const float*)W2)[src];
    W2s[dst] = f2bf(v);
  }
}

#define PPITCH 40    // bf16 cols: 80B rows, b128-aligned

struct Smem {
  alignas(16) ushort pairw[4][48 * PPITCH];  // 15360 B wave-private h1 chunk
                                             //   rows 0..31 reused for sin/cos later
  alignas(16) ushort W2l[16 * 64 * 8];       // 16384 B W2 B-frags
  alignas(16) ushort lamTf[2 * 64 * 8];      //  2048 B lambda^T B-frags
  alignas(16) float  w0d[H], w0e[H], b0e[H], b1e[H]; // 4096 B (w0d = 0.1*w0)
  alignas(16) float  b2c[NB], lamMc[NB], lamDc[NB]; // 384 B
};                                           // 38272 B

#define MFMA16(a, b, c) __builtin_amdgcn_mfma_f32_16x16x32_bf16(a, b, c, 0, 0, 0)

template<bool B16>
__device__ void pinn_body(Smem& sm,
                          const void* timeP, const void* powerP,
                          const void* W0, const void* b0,
                          const void* b1, const void* b2,
                          const void* lam_m, const void* lam_d,
                          const void* lam_b, const void* bwi,
                          const ushort* __restrict__ W1s, void* outP) {
  const int tid = threadIdx.x;
  const int wave = tid >> 6, lane = tid & 63;
  const int q = lane >> 4, r = lane & 15;

  // ================= preamble (one barrier, ONCE per 2 tiles) =================
#pragma unroll
  for (int i = 0; i < 4; i++) {
    int c = tid + i * 256;
    *(bhalf8*)(sm.W2l + c * 8) = *(const bhalf8*)(W1s + H * H + c * 8);
  }
  if (tid < 128) {   // lambda^T B-frags: lane holds lam_b[ct*16+r][q*8+j]
    int ct = tid >> 6, l2 = tid & 63, qq = l2 >> 4, rr = l2 & 15;
    BHU t;
#pragma unroll
    for (int j = 0; j < 8; j += 2)
      t.u[j >> 1] = packrne(LD<B16>(lam_b, (ct * 16 + rr) * NB + qq * 8 + j),
                            LD<B16>(lam_b, (ct * 16 + rr) * NB + qq * 8 + j + 1));
    *(bhalf8*)(sm.lamTf + tid * 8) = t.h;
  }
  if (tid < H) {
    float w0v = LD<B16>(W0, tid);
    sm.w0d[tid] = 0.1f * w0v;          // pre-fold 2/TMAX chain-rule factor
    sm.w0e[tid] = K2E * w0v;
    sm.b0e[tid] = K2E * LD<B16>(b0, tid);
    sm.b1e[tid] = K2E * LD<B16>(b1, tid);
  }
  if (tid < NB) {
    sm.b2c[tid]   = LD<B16>(b2, tid);
    sm.lamMc[tid] = LD<B16>(lam_m, tid) * LD<B16>(bwi, tid);
    sm.lamDc[tid] = LD<B16>(lam_d, tid);
  }
  __syncthreads();

  ushort* pw = &sm.pairw[wave][0];

  // ===== 2 tiles per block: 512 blocks x 2 blocks/CU = ALL co-resident;
  // one launch ramp + one preamble per CU-slot instead of two (round-0 ran
  // 1024 blocks as 2 sequential rounds) =====
#pragma unroll 1
  for (int t = 0; t < 2; ++t) {
    const int s0 = ((blockIdx.x * 2 + t) * 4 + wave) * 16;

    float tv = LD<B16>(timeP, s0 + r);
    float x = tv * 0.1f - 1.0f;               // 2t/TMAX - 1, TMAX = 20

    // ---- A-frags in registers: lane holds Ach[r][kk*32+q*8+j] ----
    bhalf8 a0f[8], a1f[8], a2f[8];
#pragma unroll
    for (int kk = 0; kk < 8; kk++) {
      int k0 = kk * 32 + q * 8;
      float4 wA = *(const float4*)&sm.w0d[k0];
      float4 wB = *(const float4*)&sm.w0d[k0 + 4];
      float4 eA = *(const float4*)&sm.w0e[k0];
      float4 eB = *(const float4*)&sm.w0e[k0 + 4];
      float4 bA = *(const float4*)&sm.b0e[k0];
      float4 bB = *(const float4*)&sm.b0e[k0 + 4];
      float w0dv[8] = {wA.x, wA.y, wA.z, wA.w, wB.x, wB.y, wB.z, wB.w};
      float w0ev[8] = {eA.x, eA.y, eA.z, eA.w, eB.x, eB.y, eB.z, eB.w};
      float b0ev[8] = {bA.x, bA.y, bA.z, bA.w, bB.x, bB.y, bB.z, bB.w};
      BHU t0, t1, t2;
      float vv[8], d1v[8], d2v[8];
#pragma unroll
      for (int j = 0; j < 8; j++) {
        float v = tanh_pf(fmaf(x, w0ev[j], b0ev[j]));
        float cc = w0dv[j];                       // = w0*0.1 (pre-folded)
        float s2 = 1.0f - v * v;
        vv[j] = v; d1v[j] = s2 * cc; d2v[j] = -2.0f * v * d1v[j] * cc;
      }
#pragma unroll
      for (int j = 0; j < 8; j += 2) {
        t0.u[j >> 1] = packtr(vv[j], vv[j + 1]);
        t1.u[j >> 1] = packtr(d1v[j], d1v[j + 1]);
        t2.u[j >> 1] = packtr(d2v[j], d2v[j + 1]);
      }
      a0f[kk] = t0.h; a1f[kk] = t1.h; a2f[kk] = t2.h;
    }

    // ---- fused GEMM1 -> tanh chain -> GEMM2; B double-buffered (bfA/bfB) ----
    f32x4 acc2[3][2];
#pragma unroll
    for (int ch = 0; ch < 3; ch++)
#pragma unroll
      for (int c2 = 0; c2 < 2; c2++) { f32x4 z = {0.f,0.f,0.f,0.f}; acc2[ch][c2] = z; }

    bhalf8 bfA[8], bfB[8];
#pragma unroll
    for (int kk = 0; kk < 8; kk++)     // preload ct=0
      bfA[kk] = *(const bhalf8*)(W1s + ((0 * 8 + kk) * 64 + lane) * 8);

#pragma unroll 1
    for (int p = 0; p < 8; p++) {
      const int ct0 = 2 * p, ct1 = 2 * p + 1;

      // issue loads for ct1 into bfB
#pragma unroll
      for (int kk = 0; kk < 8; kk++)
        bfB[kk] = *(const bhalf8*)(W1s + ((ct1 * 8 + kk) * 64 + lane) * 8);

      // GEMM1 on bfA (ct0) — arrived last iteration
      f32x4 c0 = {0.f,0.f,0.f,0.f}, c1 = c0, c2 = c0;
#pragma unroll
      for (int kk = 0; kk < 8; kk++) {
        c0 = MFMA16(a0f[kk], bfA[kk], c0);
        c1 = MFMA16(a1f[kk], bfA[kk], c1);
        c2 = MFMA16(a2f[kk], bfA[kk], c2);
      }

      // consume pair p-1 AFTER GEMM1-bfA: maximizes pw write->read gap AND
      // covers the MFMA-result latency before chain-A reads c0/c1/c2
      if (p >= 1) {
        bhalf8 hf0 = *(const bhalf8*)(pw + (0 * 16 + r) * PPITCH + q * 8);
        bhalf8 hf1 = *(const bhalf8*)(pw + (1 * 16 + r) * PPITCH + q * 8);
        bhalf8 hf2 = *(const bhalf8*)(pw + (2 * 16 + r) * PPITCH + q * 8);
#pragma unroll
        for (int c2i = 0; c2i < 2; c2i++) {
          bhalf8 w2f = *(const bhalf8*)(sm.W2l + ((c2i * 8 + (p - 1)) * 64 + lane) * 8);
          acc2[0][c2i] = MFMA16(hf0, w2f, acc2[0][c2i]);
          acc2[1][c2i] = MFMA16(hf1, w2f, acc2[1][c2i]);
          acc2[2][c2i] = MFMA16(hf2, w2f, acc2[2][c2i]);
        }
      }

      // chain-A (ct0) -> pw cols 0..15
      {
        float b1v = sm.b1e[ct0 * 16 + r];
#pragma unroll
        for (int i = 0; i < 4; i++) {
          float hv  = tanh_pf(fmaf(c0[i], K2E, b1v));
          float s2  = 1.0f - hv * hv;
          float hd  = s2 * c1[i];
          float hdd = s2 * c2[i] - 2.0f * hv * hd * c1[i];
          int row = q * 4 + i;
          pw[row * PPITCH + r]        = trunc1(hv);
          pw[(16 + row) * PPITCH + r] = trunc1(hd);
          pw[(32 + row) * PPITCH + r] = trunc1(hdd);
        }
      }

      // issue loads for ct0+2 into bfA (next pair's first buffer)
      if (p < 7) {
#pragma unroll
        for (int kk = 0; kk < 8; kk++)
          bfA[kk] = *(const bhalf8*)(W1s + (((ct0 + 2) * 8 + kk) * 64 + lane) * 8);
      }

      // GEMM1 on bfB (ct1) — latency covered by all the work above
      {
        f32x4 d0 = {0.f,0.f,0.f,0.f}, d1 = d0, d2 = d0;
#pragma unroll
        for (int kk = 0; kk < 8; kk++) {
          d0 = MFMA16(a0f[kk], bfB[kk], d0);
          d1 = MFMA16(a1f[kk], bfB[kk], d1);
          d2 = MFMA16(a2f[kk], bfB[kk], d2);
        }
        float b1v = sm.b1e[ct1 * 16 + r];
        int lc = 16 + r;
#pragma unroll
        for (int i = 0; i < 4; i++) {
          float hv  = tanh_pf(fmaf(d0[i], K2E, b1v));
          float s2  = 1.0f - hv * hv;
          float hd  = s2 * d1[i];
          float hdd = s2 * d2[i] - 2.0f * hv * hd * d1[i];
          int row = q * 4 + i;
          pw[row * PPITCH + lc]        = trunc1(hv);
          pw[(16 + row) * PPITCH + lc] = trunc1(hd);
          pw[(32 + row) * PPITCH + lc] = trunc1(hdd);
        }
      }
    }
    // final pair p=7
    {
      bhalf8 hf0 = *(const bhalf8*)(pw + (0 * 16 + r) * PPITCH + q * 8);
      bhalf8 hf1 = *(const bhalf8*)(pw + (1 * 16 + r) * PPITCH + q * 8);
      bhalf8 hf2 = *(const bhalf8*)(pw + (2 * 16 + r) * PPITCH + q * 8);
#pragma unroll
      for (int c2i = 0; c2i < 2; c2i++) {
        bhalf8 w2f = *(const bhalf8*)(sm.W2l + ((c2i * 8 + 7) * 64 + lane) * 8);
        acc2[0][c2i] = MFMA16(hf0, w2f, acc2[0][c2i]);
        acc2[1][c2i] = MFMA16(hf1, w2f, acc2[1][c2i]);
        acc2[2][c2i] = MFMA16(hf2, w2f, acc2[2][c2i]);
      }
    }

    // ---- epilogue: angles, sin/cos, coupling via MFMA, physics ----
    float dv[2][4], dt[2][4], dtt[2][4], sn[2][4], cs[2][4], Pv[2][4];
#pragma unroll
    for (int c2 = 0; c2 < 2; c2++) {
      int b = c2 * 16 + r;
      float b2v = sm.b2c[b];
#pragma unroll
      for (int i = 0; i < 4; i++) {
        int n = s0 + q * 4 + i;
        Pv[c2][i] = LD<B16>(powerP, n * NB + b);
        dv[c2][i]  = acc2[0][c2][i] + b2v;
        dt[c2][i]  = acc2[1][c2][i];
        dtt[c2][i] = acc2[2][c2][i];
        __sincosf(dv[c2][i], &sn[c2][i], &cs[c2][i]);
        // reuse pair rows: sin -> rows 0..15, cos -> rows 16..31
        pw[(q * 4 + i) * PPITCH + b]        = trunc1(sn[c2][i]);
        pw[(16 + q * 4 + i) * PPITCH + b]   = trunc1(cs[c2][i]);
        ST<B16>(outP, n * NB + b, dv[c2][i]);
        ST<B16>(outP, NPTS * NB + n * NB + b, dt[c2][i]);
      }
    }
    // coupling: C = cos @ lam^T, S = sin @ lam^T  (16x32 @ 32x32)
    bhalf8 snA = *(const bhalf8*)(pw + r * PPITCH + q * 8);
    bhalf8 csA = *(const bhalf8*)(pw + (16 + r) * PPITCH + q * 8);
    f32x4 accC[2], accS[2];
#pragma unroll
    for (int c2 = 0; c2 < 2; c2++) {
      bhalf8 lt = *(const bhalf8*)(sm.lamTf + (c2 * 64 + lane) * 8);
      f32x4 z = {0.f,0.f,0.f,0.f};
      accC[c2] = MFMA16(csA, lt, z);
      accS[c2] = MFMA16(snA, lt, z);
    }
#pragma unroll
    for (int c2 = 0; c2 < 2; c2++) {
      int b = c2 * 16 + r;
      float lm = sm.lamMc[b], ldv = sm.lamDc[b];
#pragma unroll
      for (int i = 0; i < 4; i++) {
        float conn = sn[c2][i] * accC[c2][i] - cs[c2][i] * accS[c2][i];
        float phys = lm * dtt[c2][i] + ldv * dt[c2][i] + conn - Pv[c2][i];
        int n = s0 + q * 4 + i;
        ST<B16>(outP, 2 * NPTS * NB + n * NB + b, phys);
      }
    }
  }
}

// (256,2): VGPR cap 256 — no spills (proven: (256,3)/(256,4) both spilled).
__global__ __launch_bounds__(256, 2)
void pinn_kernel(const void* timeP, const void* powerP,
                 const void* W0, const void* b0,
                 const void* b1, const void* b2,
                 const void* lam_m, const void* lam_d,
                 const void* lam_b, const void* bwi,
                 const void* W1_for_detect,
                 const ushort* __restrict__ W1s, void* outP) {
  __shared__ Smem sm;
  if (detect_bf16(W1_for_detect))
    pinn_body<true>(sm, timeP, powerP, W0, b0, b1, b2, lam_m, lam_d, lam_b, bwi,
                    W1s, outP);
  else
    pinn_body<false>(sm, timeP, powerP, W0, b0, b1, b2, lam_m, lam_d, lam_b, bwi,
                     W1s, outP);
}

extern "C" void kernel_launch(void* const* d_in, const int* in_sizes, int n_in,
                              void* d_out, int out_size, void* d_ws, size_t ws_size,
                              hipStream_t stream) {
  const void* timeP  = d_in[0];
  const void* powerP = d_in[1];
  const void* W0     = d_in[2];
  const void* b0     = d_in[3];
  const void* W1     = d_in[4];
  const void* b1     = d_in[5];
  const void* W2     = d_in[6];
  const void* b2     = d_in[7];
  const void* lam_m  = d_in[8];
  const void* lam_d  = d_in[9];
  const void* lam_b  = d_in[10];
  const void* bwi    = d_in[11];

  ushort* W1s = (ushort*)d_ws;            // W1 frags 128 KB; W2 frags at +65536
  ushort* W2s = W1s + H * H;

  swz_kernel<<<288, 256, 0, stream>>>(W1, W2, W1s, W2s);
  pinn_kernel<<<512, 256, 0, stream>>>(timeP, powerP, W0, b0, b1, b2,
                                       lam_m, lam_d, lam_b, bwi, W1,
                                       W1s, d_out);
  (void)W2s;
}